// Round 1
// baseline (1381.993 us; speedup 1.0000x reference)
//
#include <hip/hip_runtime.h>
#include <hip/hip_bf16.h>

typedef __bf16 bf16;
typedef __attribute__((ext_vector_type(8))) __bf16 bf16x8;
typedef __attribute__((ext_vector_type(4))) __bf16 bf16x4;
typedef __attribute__((ext_vector_type(4))) float f32x4;

constexpr int N_NODES   = 100000;
constexpr int N_PAD     = 100032;   // multiple of 64 (GEMM block tile)
constexpr int N_EDGES   = 3200000;
constexpr int D         = 128;
constexpr int D_FF      = 256;
constexpr int N_CLASSES = 26;
constexpr int N_GRAPHS  = 512;

// ---------------- graph preprocessing ----------------

__global__ void init_kernel(int* counts, int* fillc, int* starts, int n) {
    int i = blockIdx.x * 256 + threadIdx.x;
    if (i < n) { counts[i] = 1; fillc[i] = 0; }   // 1 = self-loop
    if (i <= N_GRAPHS) starts[i] = n;             // sentinel
}

__global__ void hist_kernel(const int* __restrict__ edst, int* counts, int e) {
    int i = blockIdx.x * 256 + threadIdx.x;
    if (i < e) atomicAdd(&counts[edst[i]], 1);
}

__global__ void dinv_kernel(const int* __restrict__ counts, float* dinv, int n) {
    int i = blockIdx.x * 256 + threadIdx.x;
    if (i < n) dinv[i] = 1.0f / sqrtf((float)counts[i]);
}

// 3-phase exclusive scan of counts -> rowptr (rowptr[0]=0, rowptr[i+1]=incl[i])
__global__ __launch_bounds__(256) void scan1(const int* __restrict__ counts,
                                             int* rowptr, int* bsum, int n) {
    __shared__ int sd[256];
    int i = blockIdx.x * 256 + threadIdx.x;
    int v = (i < n) ? counts[i] : 0;
    sd[threadIdx.x] = v; __syncthreads();
    for (int off = 1; off < 256; off <<= 1) {
        int t = (threadIdx.x >= off) ? sd[threadIdx.x - off] : 0;
        __syncthreads();
        sd[threadIdx.x] += t;
        __syncthreads();
    }
    if (i < n) rowptr[i + 1] = sd[threadIdx.x];
    if (threadIdx.x == 255) bsum[blockIdx.x] = sd[255];
}

__global__ __launch_bounds__(512) void scan2(const int* __restrict__ bsum,
                                             int* boff, int nb) {
    __shared__ int sd[512];
    int t = threadIdx.x;
    int v = (t < nb) ? bsum[t] : 0;
    sd[t] = v; __syncthreads();
    for (int off = 1; off < 512; off <<= 1) {
        int x = (t >= off) ? sd[t - off] : 0;
        __syncthreads();
        sd[t] += x;
        __syncthreads();
    }
    if (t < nb) boff[t] = sd[t] - v;  // exclusive
}

__global__ void scan3(int* rowptr, const int* __restrict__ boff, int n) {
    int i = blockIdx.x * 256 + threadIdx.x;
    if (i < n) rowptr[i + 1] += boff[blockIdx.x];
    if (i == 0) rowptr[0] = 0;
}

__global__ void fill_self(const int* __restrict__ rowptr, int* fillc,
                          int* csrc, float* cnorm, const float* __restrict__ dinv, int n) {
    int i = blockIdx.x * 256 + threadIdx.x;
    if (i >= n) return;
    int pos = rowptr[i] + atomicAdd(&fillc[i], 1);
    csrc[pos] = i;
    cnorm[pos] = dinv[i] * dinv[i];
}

__global__ void fill_edges(const int* __restrict__ esrc, const int* __restrict__ edst,
                           const int* __restrict__ rowptr, int* fillc,
                           int* csrc, float* cnorm, const float* __restrict__ dinv, int e) {
    int i = blockIdx.x * 256 + threadIdx.x;
    if (i >= e) return;
    int s = esrc[i], d = edst[i];
    int pos = rowptr[d] + atomicAdd(&fillc[d], 1);
    csrc[pos] = s;
    cnorm[pos] = dinv[s] * dinv[d];
}

__global__ void find_starts(const int* __restrict__ batch, int* starts, int n) {
    int i = blockIdx.x * 256 + threadIdx.x;
    if (i >= n) return;
    int b = batch[i];
    if (i == 0 || batch[i - 1] != b) atomicMin(&starts[b], i);
}

__global__ void fix_starts(int* starts) {
    if (blockIdx.x == 0 && threadIdx.x == 0) {
        for (int g = N_GRAPHS - 1; g >= 0; --g)
            if (starts[g] > starts[g + 1]) starts[g] = starts[g + 1];
    }
}

// ---------------- dense compute ----------------

// f32 -> bf16 cast, 4 elems/thread; pads tail rows with zeros
__global__ void cast4_kernel(const float* __restrict__ src, bf16* __restrict__ dst,
                             int nvalid, int ntotal) {
    int i = (blockIdx.x * 256 + threadIdx.x) * 4;
    if (i >= ntotal) return;
    float4 v = make_float4(0.f, 0.f, 0.f, 0.f);
    if (i < nvalid) v = *(const float4*)(src + i);
    bf16x4 o = { (bf16)v.x, (bf16)v.y, (bf16)v.z, (bf16)v.w };
    *(bf16x4*)(dst + i) = o;
}

// W[k][n] f32 -> WT[n][k] bf16 (32 KB, reused by every GEMM block)
__global__ void castWT_kernel(const float* __restrict__ W, bf16* __restrict__ WT) {
    int n = blockIdx.x, k = threadIdx.x;
    WT[n * D + k] = (bf16)W[k * D + n];
}

// C[Mpad x 128] = A[Mpad x 128] @ W[128 x 128], bf16 MFMA, no LDS.
// Block = 4 waves, each wave does a 16-row x 128-col stripe; K=128 fully unrolled.
__global__ __launch_bounds__(256) void gemm_kernel(const bf16* __restrict__ A,
                                                   const bf16* __restrict__ WT,
                                                   float* __restrict__ C) {
    int wave = threadIdx.x >> 6;
    int lane = threadIdx.x & 63;
    int m16  = lane & 15;
    int quad = lane >> 4;
    int row0 = blockIdx.x * 64 + wave * 16;

    bf16x8 a[4];
    const bf16* arow = A + (row0 + m16) * D + quad * 8;
#pragma unroll
    for (int kt = 0; kt < 4; ++kt)
        a[kt] = *(const bf16x8*)(arow + kt * 32);

#pragma unroll
    for (int nt = 0; nt < 8; ++nt) {
        f32x4 acc = {0.f, 0.f, 0.f, 0.f};
        const bf16* brow = WT + (nt * 16 + m16) * D + quad * 8;
#pragma unroll
        for (int kt = 0; kt < 4; ++kt) {
            bf16x8 b = *(const bf16x8*)(brow + kt * 32);
            acc = __builtin_amdgcn_mfma_f32_16x16x32_bf16(a[kt], b, acc, 0, 0, 0);
        }
#pragma unroll
        for (int r = 0; r < 4; ++r)
            C[(row0 + quad * 4 + r) * D + nt * 16 + m16] = acc[r];
    }
}

// out[v][d] = relu( sum_{e in CSR row v} norm_e * h[src_e][d] + bias[d] )
__global__ __launch_bounds__(128) void spmm_kernel(const float* __restrict__ h,
                                                   const int* __restrict__ rowptr,
                                                   const int* __restrict__ csrc,
                                                   const float* __restrict__ cnorm,
                                                   const float* __restrict__ bias,
                                                   float* __restrict__ out) {
    int node = blockIdx.x;
    int d = threadIdx.x;
    int s = rowptr[node], e = rowptr[node + 1];
    float acc = 0.f;
    int j = s;
    for (; j + 4 <= e; j += 4) {
        int i0 = csrc[j], i1 = csrc[j + 1], i2 = csrc[j + 2], i3 = csrc[j + 3];
        float w0 = cnorm[j], w1 = cnorm[j + 1], w2 = cnorm[j + 2], w3 = cnorm[j + 3];
        float v0 = h[i0 * D + d], v1 = h[i1 * D + d];
        float v2 = h[i2 * D + d], v3 = h[i3 * D + d];
        acc = fmaf(w0, v0, acc);
        acc = fmaf(w1, v1, acc);
        acc = fmaf(w2, v2, acc);
        acc = fmaf(w3, v3, acc);
    }
    for (; j < e; ++j) acc = fmaf(cnorm[j], h[csrc[j] * D + d], acc);
    acc += bias[d];
    out[node * D + d] = fmaxf(acc, 0.f);
}

__global__ __launch_bounds__(128) void pool_kernel(const float* __restrict__ h,
                                                   const int* __restrict__ starts,
                                                   float* __restrict__ pooled) {
    int g = blockIdx.x, d = threadIdx.x;
    int s = starts[g], e = starts[g + 1];
    float acc = 0.f;
    for (int r = s; r < e; ++r) acc += h[r * D + d];
    pooled[g * D + d] = acc / fmaxf((float)(e - s), 1.0f);
}

__global__ __launch_bounds__(256) void fc_kernel(const float* __restrict__ pooled,
                                                 const float* __restrict__ Wfc,
                                                 const float* __restrict__ bfc,
                                                 const float* __restrict__ Wfc2,
                                                 const float* __restrict__ bfc2,
                                                 float* __restrict__ out) {
    __shared__ float pr[D];
    __shared__ float hid[D_FF];
    int g = blockIdx.x, t = threadIdx.x;
    if (t < D) pr[t] = pooled[g * D + t];
    __syncthreads();
    float acc = bfc[t];
    for (int k = 0; k < D; ++k) acc = fmaf(pr[k], Wfc[k * D_FF + t], acc);
    hid[t] = fmaxf(acc, 0.f);
    __syncthreads();
    if (t < N_CLASSES) {
        float o = bfc2[t];
        for (int k = 0; k < D_FF; ++k) o = fmaf(hid[k], Wfc2[k * N_CLASSES + t], o);
        out[g * N_CLASSES + t] = o;
    }
}

// ---------------- launch ----------------

extern "C" void kernel_launch(void* const* d_in, const int* in_sizes, int n_in,
                              void* d_out, int out_size, void* d_ws, size_t ws_size,
                              hipStream_t stream) {
    const float* x     = (const float*)d_in[0];
    const int*   eidx  = (const int*)d_in[1];
    const int*   batch = (const int*)d_in[2];
    const float* W[3]  = { (const float*)d_in[3], (const float*)d_in[5], (const float*)d_in[7] };
    const float* b[3]  = { (const float*)d_in[4], (const float*)d_in[6], (const float*)d_in[8] };
    const float* Wfc   = (const float*)d_in[9];
    const float* bfc   = (const float*)d_in[10];
    const float* Wfc2  = (const float*)d_in[11];
    const float* bfc2  = (const float*)d_in[12];
    float* out = (float*)d_out;

    const int E = in_sizes[1] / 2;           // 3,200,000
    const int N = in_sizes[0] / D;           // 100,000
    const int* esrc = eidx;
    const int* edst = eidx + E;

    // workspace carve-up (256B aligned)
    uint8_t* base = (uint8_t*)d_ws;
    size_t off = 0;
    auto alloc = [&](size_t bytes) -> void* {
        void* p = base + off;
        off = (off + bytes + 255) & ~(size_t)255;
        return p;
    };
    float* hA     = (float*)alloc((size_t)N_PAD * D * 4);   // gemm out
    float* hB     = (float*)alloc((size_t)N_PAD * D * 4);   // spmm out
    bf16*  Xb     = (bf16*) alloc((size_t)N_PAD * D * 2);   // gemm A (bf16)
    bf16*  WT     = (bf16*) alloc((size_t)D * D * 2);
    int*   csrc   = (int*)  alloc((size_t)(E + N) * 4);
    float* cnorm  = (float*)alloc((size_t)(E + N) * 4);
    int*   counts = (int*)  alloc((size_t)N * 4);
    int*   fillc  = (int*)  alloc((size_t)N * 4);
    int*   rowptr = (int*)  alloc((size_t)(N + 1) * 4);
    float* dinv   = (float*)alloc((size_t)N * 4);
    int*   bsum   = (int*)  alloc(4096);
    int*   boff   = (int*)  alloc(4096);
    int*   starts = (int*)  alloc((size_t)(N_GRAPHS + 1) * 4);
    float* pooled = (float*)alloc((size_t)N_GRAPHS * D * 4);
    (void)ws_size; (void)n_in; (void)out_size;

    const int NB  = (N + 255) / 256;          // 391
    const int EB  = (E + 255) / 256;          // 12500
    const int CB  = (N_PAD * D / 4 + 255) / 256;
    const int GB  = N_PAD / 64;               // 1563

    // graph structure (once per launch, shared by all 3 layers)
    init_kernel<<<NB, 256, 0, stream>>>(counts, fillc, starts, N);
    hist_kernel<<<EB, 256, 0, stream>>>(edst, counts, E);
    dinv_kernel<<<NB, 256, 0, stream>>>(counts, dinv, N);
    scan1<<<NB, 256, 0, stream>>>(counts, rowptr, bsum, N);
    scan2<<<1, 512, 0, stream>>>(bsum, boff, NB);
    scan3<<<NB, 256, 0, stream>>>(rowptr, boff, N);
    fill_self<<<NB, 256, 0, stream>>>(rowptr, fillc, csrc, cnorm, dinv, N);
    fill_edges<<<EB, 256, 0, stream>>>(esrc, edst, rowptr, fillc, csrc, cnorm, dinv, E);
    find_starts<<<NB, 256, 0, stream>>>(batch, starts, N);
    fix_starts<<<1, 64, 0, stream>>>(starts);

    // 3 GCN layers
    const float* layer_in = x;
    for (int l = 0; l < 3; ++l) {
        castWT_kernel<<<D, D, 0, stream>>>(W[l], WT);
        cast4_kernel<<<CB, 256, 0, stream>>>(layer_in, Xb, N * D, N_PAD * D);
        gemm_kernel<<<GB, 256, 0, stream>>>(Xb, WT, hA);
        spmm_kernel<<<N, 128, 0, stream>>>(hA, rowptr, csrc, cnorm, b[l], hB);
        layer_in = hB;
    }

    // readout
    pool_kernel<<<N_GRAPHS, 128, 0, stream>>>(hB, starts, pooled);
    fc_kernel<<<N_GRAPHS, 256, 0, stream>>>(pooled, Wfc, bfc, Wfc2, bfc2, out);
}

// Round 2
// 868.203 us; speedup vs baseline: 1.5918x; 1.5918x over previous
//
#include <hip/hip_runtime.h>
#include <hip/hip_bf16.h>

typedef __bf16 bf16;
typedef __attribute__((ext_vector_type(8))) __bf16 bf16x8;
typedef __attribute__((ext_vector_type(4))) __bf16 bf16x4;
typedef __attribute__((ext_vector_type(2))) __bf16 bf16x2;
typedef __attribute__((ext_vector_type(4))) float f32x4;

constexpr int N_NODES   = 100000;
constexpr int N_PAD     = 100032;   // multiple of 64 (GEMM block tile)
constexpr int D         = 128;
constexpr int D_FF      = 256;
constexpr int N_CLASSES = 26;
constexpr int N_GRAPHS  = 512;

__device__ inline float2 bf2f(unsigned u) {
    float lo = __uint_as_float(u << 16);
    float hi = __uint_as_float(u & 0xffff0000u);
    return make_float2(lo, hi);
}

// ---------------- graph preprocessing ----------------

__global__ void init_kernel(int* counts, int* starts, int n) {
    int i = blockIdx.x * 256 + threadIdx.x;
    if (i < n) counts[i] = 0;                  // edges only; self handled in spmm
    if (i <= N_GRAPHS) starts[i] = n;          // sentinel
}

// per-edge within-row offset comes free from the histogram atomic
__global__ void hist_kernel(const int* __restrict__ edst, int* counts,
                            int* __restrict__ eoff, int e) {
    int i = blockIdx.x * 256 + threadIdx.x;
    if (i < e) eoff[i] = atomicAdd(&counts[edst[i]], 1);
}

__global__ void dinv_kernel(const int* __restrict__ counts, float* dinv, int n) {
    int i = blockIdx.x * 256 + threadIdx.x;
    if (i < n) dinv[i] = 1.0f / sqrtf((float)(counts[i] + 1));  // +1 = self-loop
}

// 3-phase exclusive scan of counts -> rowptr
__global__ __launch_bounds__(256) void scan1(const int* __restrict__ counts,
                                             int* rowptr, int* bsum, int n) {
    __shared__ int sd[256];
    int i = blockIdx.x * 256 + threadIdx.x;
    int v = (i < n) ? counts[i] : 0;
    sd[threadIdx.x] = v; __syncthreads();
    for (int off = 1; off < 256; off <<= 1) {
        int t = (threadIdx.x >= off) ? sd[threadIdx.x - off] : 0;
        __syncthreads();
        sd[threadIdx.x] += t;
        __syncthreads();
    }
    if (i < n) rowptr[i + 1] = sd[threadIdx.x];
    if (threadIdx.x == 255) bsum[blockIdx.x] = sd[255];
}

__global__ __launch_bounds__(512) void scan2(const int* __restrict__ bsum,
                                             int* boff, int nb) {
    __shared__ int sd[512];
    int t = threadIdx.x;
    int v = (t < nb) ? bsum[t] : 0;
    sd[t] = v; __syncthreads();
    for (int off = 1; off < 512; off <<= 1) {
        int x = (t >= off) ? sd[t - off] : 0;
        __syncthreads();
        sd[t] += x;
        __syncthreads();
    }
    if (t < nb) boff[t] = sd[t] - v;  // exclusive
}

__global__ void scan3(int* rowptr, const int* __restrict__ boff, int n) {
    int i = blockIdx.x * 256 + threadIdx.x;
    if (i < n) rowptr[i + 1] += boff[blockIdx.x];
    if (i == 0) rowptr[0] = 0;
}

// single scattered 4B write per edge (was 2 arrays + atomic before)
__global__ void fill_edges(const int* __restrict__ esrc, const int* __restrict__ edst,
                           const int* __restrict__ eoff, const int* __restrict__ rowptr,
                           int* __restrict__ csrc, int e) {
    int i = blockIdx.x * 256 + threadIdx.x;
    if (i >= e) return;
    csrc[rowptr[edst[i]] + eoff[i]] = esrc[i];
}

__global__ void find_starts(const int* __restrict__ batch, int* starts, int n) {
    int i = blockIdx.x * 256 + threadIdx.x;
    if (i >= n) return;
    int b = batch[i];
    if (i == 0 || batch[i - 1] != b) atomicMin(&starts[b], i);
}

__global__ void fix_starts(int* starts) {
    if (blockIdx.x == 0 && threadIdx.x == 0) {
        for (int g = N_GRAPHS - 1; g >= 0; --g)
            if (starts[g] > starts[g + 1]) starts[g] = starts[g + 1];
    }
}

// ---------------- dense compute ----------------

// f32 -> bf16 cast (layer-1 input only), zero-pads tail rows
__global__ void cast4_kernel(const float* __restrict__ src, bf16* __restrict__ dst,
                             int nvalid, int ntotal) {
    int i = (blockIdx.x * 256 + threadIdx.x) * 4;
    if (i >= ntotal) return;
    float4 v = make_float4(0.f, 0.f, 0.f, 0.f);
    if (i < nvalid) v = *(const float4*)(src + i);
    bf16x4 o = { (bf16)v.x, (bf16)v.y, (bf16)v.z, (bf16)v.w };
    *(bf16x4*)(dst + i) = o;
}

// W[k][n] f32 -> WT[n][k] bf16
__global__ void castWT_kernel(const float* __restrict__ W, bf16* __restrict__ WT) {
    int n = blockIdx.x, k = threadIdx.x;
    WT[n * D + k] = (bf16)W[k * D + n];
}

// C[Mpad x 128] = A[Mpad x 128] @ W[128 x 128], bf16 in/out, no LDS.
__global__ __launch_bounds__(256) void gemm_kernel(const bf16* __restrict__ A,
                                                   const bf16* __restrict__ WT,
                                                   bf16* __restrict__ C) {
    int wave = threadIdx.x >> 6;
    int lane = threadIdx.x & 63;
    int m16  = lane & 15;
    int quad = lane >> 4;
    int row0 = blockIdx.x * 64 + wave * 16;

    bf16x8 a[4];
    const bf16* arow = A + (row0 + m16) * D + quad * 8;
#pragma unroll
    for (int kt = 0; kt < 4; ++kt)
        a[kt] = *(const bf16x8*)(arow + kt * 32);

#pragma unroll
    for (int nt = 0; nt < 8; ++nt) {
        f32x4 acc = {0.f, 0.f, 0.f, 0.f};
        const bf16* brow = WT + (nt * 16 + m16) * D + quad * 8;
#pragma unroll
        for (int kt = 0; kt < 4; ++kt) {
            bf16x8 b = *(const bf16x8*)(brow + kt * 32);
            acc = __builtin_amdgcn_mfma_f32_16x16x32_bf16(a[kt], b, acc, 0, 0, 0);
        }
#pragma unroll
        for (int r = 0; r < 4; ++r)
            C[(row0 + quad * 4 + r) * D + nt * 16 + m16] = (bf16)acc[r];
    }
}

// out[v][:] = relu( dinv[v]^2*h[v] + sum_e dinv[src]*dinv[v]*h[src] + bias )
// one wave per node; lane covers dims {2*lane, 2*lane+1} as packed bf16x2
__global__ __launch_bounds__(64) void spmm_kernel(const bf16* __restrict__ h,
                                                  const int* __restrict__ rowptr,
                                                  const int* __restrict__ csrc,
                                                  const float* __restrict__ dinv,
                                                  const float* __restrict__ bias,
                                                  bf16* __restrict__ out) {
    int v = blockIdx.x;
    int lane = threadIdx.x;
    int s = rowptr[v], e = rowptr[v + 1];
    float dv = dinv[v];

    // self-loop term
    unsigned su = *(const unsigned*)(h + v * D + lane * 2);
    float2 sf = bf2f(su);
    float accx = dv * dv * sf.x;
    float accy = dv * dv * sf.y;

    for (int j0 = s; j0 < e; j0 += 64) {
        int n = min(64, e - j0);
        int idx = 0; float w = 0.f;
        if (j0 + lane < e) { idx = csrc[j0 + lane]; w = dinv[idx]; }
        int t = 0;
        for (; t + 4 <= n; t += 4) {
            int s0 = __shfl(idx, t),     s1 = __shfl(idx, t + 1);
            int s2 = __shfl(idx, t + 2), s3 = __shfl(idx, t + 3);
            float w0 = __shfl(w, t) * dv,     w1 = __shfl(w, t + 1) * dv;
            float w2 = __shfl(w, t + 2) * dv, w3 = __shfl(w, t + 3) * dv;
            unsigned u0 = *(const unsigned*)(h + s0 * D + lane * 2);
            unsigned u1 = *(const unsigned*)(h + s1 * D + lane * 2);
            unsigned u2 = *(const unsigned*)(h + s2 * D + lane * 2);
            unsigned u3 = *(const unsigned*)(h + s3 * D + lane * 2);
            float2 f0 = bf2f(u0), f1 = bf2f(u1), f2 = bf2f(u2), f3 = bf2f(u3);
            accx = fmaf(w0, f0.x, accx); accy = fmaf(w0, f0.y, accy);
            accx = fmaf(w1, f1.x, accx); accy = fmaf(w1, f1.y, accy);
            accx = fmaf(w2, f2.x, accx); accy = fmaf(w2, f2.y, accy);
            accx = fmaf(w3, f3.x, accx); accy = fmaf(w3, f3.y, accy);
        }
        for (; t < n; ++t) {
            int src = __shfl(idx, t);
            float wt = __shfl(w, t) * dv;
            unsigned u = *(const unsigned*)(h + src * D + lane * 2);
            float2 f = bf2f(u);
            accx = fmaf(wt, f.x, accx);
            accy = fmaf(wt, f.y, accy);
        }
    }

    accx = fmaxf(accx + bias[lane * 2], 0.f);
    accy = fmaxf(accy + bias[lane * 2 + 1], 0.f);
    bf16x2 o = { (bf16)accx, (bf16)accy };
    *(bf16x2*)(out + v * D + lane * 2) = o;
}

__global__ __launch_bounds__(64) void pool_kernel(const bf16* __restrict__ h,
                                                  const int* __restrict__ starts,
                                                  float* __restrict__ pooled) {
    int g = blockIdx.x, lane = threadIdx.x;
    int s = starts[g], e = starts[g + 1];
    float ax = 0.f, ay = 0.f;
    for (int r = s; r < e; ++r) {
        unsigned u = *(const unsigned*)(h + r * D + lane * 2);
        float2 f = bf2f(u);
        ax += f.x; ay += f.y;
    }
    float c = fmaxf((float)(e - s), 1.0f);
    pooled[g * D + lane * 2]     = ax / c;
    pooled[g * D + lane * 2 + 1] = ay / c;
}

__global__ __launch_bounds__(256) void fc_kernel(const float* __restrict__ pooled,
                                                 const float* __restrict__ Wfc,
                                                 const float* __restrict__ bfc,
                                                 const float* __restrict__ Wfc2,
                                                 const float* __restrict__ bfc2,
                                                 float* __restrict__ out) {
    __shared__ float pr[D];
    __shared__ float hid[D_FF];
    int g = blockIdx.x, t = threadIdx.x;
    if (t < D) pr[t] = pooled[g * D + t];
    __syncthreads();
    float acc = bfc[t];
    for (int k = 0; k < D; ++k) acc = fmaf(pr[k], Wfc[k * D_FF + t], acc);
    hid[t] = fmaxf(acc, 0.f);
    __syncthreads();
    if (t < N_CLASSES) {
        float o = bfc2[t];
        for (int k = 0; k < D_FF; ++k) o = fmaf(hid[k], Wfc2[k * N_CLASSES + t], o);
        out[g * N_CLASSES + t] = o;
    }
}

// ---------------- launch ----------------

extern "C" void kernel_launch(void* const* d_in, const int* in_sizes, int n_in,
                              void* d_out, int out_size, void* d_ws, size_t ws_size,
                              hipStream_t stream) {
    const float* x     = (const float*)d_in[0];
    const int*   eidx  = (const int*)d_in[1];
    const int*   batch = (const int*)d_in[2];
    const float* W[3]  = { (const float*)d_in[3], (const float*)d_in[5], (const float*)d_in[7] };
    const float* b[3]  = { (const float*)d_in[4], (const float*)d_in[6], (const float*)d_in[8] };
    const float* Wfc   = (const float*)d_in[9];
    const float* bfc   = (const float*)d_in[10];
    const float* Wfc2  = (const float*)d_in[11];
    const float* bfc2  = (const float*)d_in[12];
    float* out = (float*)d_out;

    const int E = in_sizes[1] / 2;           // 3,200,000
    const int N = in_sizes[0] / D;           // 100,000
    const int* esrc = eidx;
    const int* edst = eidx + E;

    uint8_t* base = (uint8_t*)d_ws;
    size_t off = 0;
    auto alloc = [&](size_t bytes) -> void* {
        void* p = base + off;
        off = (off + bytes + 255) & ~(size_t)255;
        return p;
    };
    bf16*  hA     = (bf16*) alloc((size_t)N_PAD * D * 2);   // gemm out
    bf16*  hB     = (bf16*) alloc((size_t)N_PAD * D * 2);   // spmm out
    bf16*  Xb     = (bf16*) alloc((size_t)N_PAD * D * 2);   // layer-1 gemm A
    bf16*  WT     = (bf16*) alloc((size_t)D * D * 2);
    int*   csrc   = (int*)  alloc((size_t)E * 4);
    int*   eoff   = (int*)  alloc((size_t)E * 4);
    int*   counts = (int*)  alloc((size_t)N * 4);
    int*   rowptr = (int*)  alloc((size_t)(N + 1) * 4);
    float* dinv   = (float*)alloc((size_t)N * 4);
    int*   bsum   = (int*)  alloc(4096);
    int*   boff   = (int*)  alloc(4096);
    int*   starts = (int*)  alloc((size_t)(N_GRAPHS + 1) * 4);
    float* pooled = (float*)alloc((size_t)N_GRAPHS * D * 4);
    (void)ws_size; (void)n_in; (void)out_size;

    const int NB  = (N + 255) / 256;          // 391
    const int EB  = (E + 255) / 256;          // 12500
    const int CB  = (N_PAD * D / 4 + 255) / 256;
    const int GB  = N_PAD / 64;               // 1563

    init_kernel<<<NB, 256, 0, stream>>>(counts, starts, N);
    hist_kernel<<<EB, 256, 0, stream>>>(edst, counts, eoff, E);
    dinv_kernel<<<NB, 256, 0, stream>>>(counts, dinv, N);
    scan1<<<NB, 256, 0, stream>>>(counts, rowptr, bsum, N);
    scan2<<<1, 512, 0, stream>>>(bsum, boff, NB);
    scan3<<<NB, 256, 0, stream>>>(rowptr, boff, N);
    fill_edges<<<EB, 256, 0, stream>>>(esrc, edst, eoff, rowptr, csrc, E);
    find_starts<<<NB, 256, 0, stream>>>(batch, starts, N);
    fix_starts<<<1, 64, 0, stream>>>(starts);

    cast4_kernel<<<CB, 256, 0, stream>>>(x, Xb, N * D, N_PAD * D);

    const bf16* layer_in = Xb;
    for (int l = 0; l < 3; ++l) {
        castWT_kernel<<<D, D, 0, stream>>>(W[l], WT);
        gemm_kernel<<<GB, 256, 0, stream>>>(layer_in, WT, hA);
        spmm_kernel<<<N, 64, 0, stream>>>(hA, rowptr, csrc, dinv, b[l], hB);
        layer_in = hB;
    }

    pool_kernel<<<N_GRAPHS, 64, 0, stream>>>(hB, starts, pooled);
    fc_kernel<<<N_GRAPHS, 256, 0, stream>>>(pooled, Wfc, bfc, Wfc2, bfc2, out);
}